// Round 10
// baseline (218.442 us; speedup 1.0000x reference)
//
#include <hip/hip_runtime.h>
#include <stdint.h>

// Problem constants (B=4, S=2048, H=1024, E=8, M=512, K=2, SM=1024, G=64)
#define T_TOK 8192
#define H_DIM 1024
#define M_DIM 512
#define SM_DIM 1024
#define E_NUM 8
#define S_SEQ 2048
#define G_DIM 64
#define NASSIGN 16384                      // T_TOK * 2
#define NSLOT (NASSIGN + E_NUM * 256)      // compact slots + per-expert 256-tile padding
#define MAX_TILES (NASSIGN / 256 + E_NUM)  // 72
#define NBLK_PLACE (NASSIGN / 256)         // 64
#define NT_W 3840                          // 64x64 weight transpose tiles

typedef float f32x4 __attribute__((ext_vector_type(4)));
typedef short bf16x8 __attribute__((ext_vector_type(8)));

struct TileDesc { int base; int expert; int nrows; };

#define WAITCNT_VM0 asm volatile("s_waitcnt vmcnt(0)" ::: "memory")

static __device__ __forceinline__ ushort f2b(float f) {
  union { float f; uint32_t u; } a; a.f = f;
  uint32_t r = a.u + 0x7fffu + ((a.u >> 16) & 1u);  // RNE
  return (ushort)(r >> 16);
}
static __device__ __forceinline__ float b2f(ushort u) {
  union { uint32_t u; float f; } a; a.u = ((uint32_t)u) << 16;
  return a.f;
}
static __device__ __forceinline__ int imin(int a, int b) { return a < b ? a : b; }

// async global->LDS, 16B per lane; LDS dest = wave-uniform base + lane*16
static __device__ __forceinline__ void gll16(const void* g, void* l) {
  __builtin_amdgcn_global_load_lds(
      (const __attribute__((address_space(1))) void*)g,
      (__attribute__((address_space(3))) void*)l, 16, 0, 0);
}
// XCD-chunked bijective remap (nwg divisible by 8)
static __device__ __forceinline__ int xcd_remap(int wg, int nwg) {
  return (wg & 7) * (nwg >> 3) + (wg >> 3);
}

// ---------------- prep: 64x64 weight transpose tiles + fused router + hist ----------
__global__ __launch_bounds__(256) void prep_kernel(
    const float* __restrict__ x, const float* __restrict__ wt, const float* __restrict__ g,
    const float* __restrict__ wgm,
    const float* __restrict__ w_gate, const float* __restrict__ w_up,
    const float* __restrict__ w_down, const float* __restrict__ sw_gate,
    const float* __restrict__ sw_up, const float* __restrict__ sw_down,
    ushort* __restrict__ wg_t, ushort* __restrict__ wu_t,
    ushort* __restrict__ wd_t, ushort* __restrict__ swg_t,
    ushort* __restrict__ swu_t, ushort* __restrict__ swd_t,
    ushort* __restrict__ xb, int* __restrict__ tidx, float* __restrict__ tw,
    int* __restrict__ bcount) {
  __shared__ float tile[64][65];
  int id = blockIdx.x;
  int tid = threadIdx.x;
  if (id < NT_W) {
    int tx = tid & 15, ty = tid >> 4;
    const float* src; ushort* dst; int R, C, t;
    if (id < 1024)        { src = w_gate;  dst = wg_t;  R = 1024; C = 512;  t = id; }
    else if (id < 2048)   { src = w_up;    dst = wu_t;  R = 1024; C = 512;  t = id - 1024; }
    else if (id < 3072)   { src = w_down;  dst = wd_t;  R = 512;  C = 1024; t = id - 2048; }
    else if (id < 3328)   { src = sw_gate; dst = swg_t; R = 1024; C = 1024; t = id - 3072; }
    else if (id < 3584)   { src = sw_up;   dst = swu_t; R = 1024; C = 1024; t = id - 3328; }
    else                  { src = sw_down; dst = swd_t; R = 1024; C = 1024; t = id - 3584; }
    int tc = C >> 6;
    int tpm = (R >> 6) * tc;
    int e = t / tpm, tt = t % tpm;
    int c0 = (tt % tc) * 64, r0 = (tt / tc) * 64;
    size_t bo = (size_t)e * R * C;
    src += bo; dst += bo;
#pragma unroll
    for (int p = 0; p < 4; ++p) {
      int row = ty + p * 16;
      float4 v = *(const float4*)&src[(size_t)(r0 + row) * C + c0 + tx * 4];
      tile[row][tx * 4 + 0] = v.x; tile[row][tx * 4 + 1] = v.y;
      tile[row][tx * 4 + 2] = v.z; tile[row][tx * 4 + 3] = v.w;
    }
    __syncthreads();
#pragma unroll
    for (int p = 0; p < 4; ++p) {
      int cc = ty + p * 16;
      ushort4 o;
      o.x = f2b(tile[tx * 4 + 0][cc]); o.y = f2b(tile[tx * 4 + 1][cc]);
      o.z = f2b(tile[tx * 4 + 2][cc]); o.w = f2b(tile[tx * 4 + 3][cc]);
      *(ushort4*)&dst[(size_t)(c0 + cc) * R + r0 + tx * 4] = o;
    }
    return;
  }
  // ---- router (4 tokens per block, 1 wave each) ----
  int id2 = id - NT_W;
  int wv = tid >> 6, lane = tid & 63;
  int t = id2 * 4 + wv;
  const float4* xr4 = (const float4*)x + (size_t)t * 256;
  ushort4* xb4 = (ushort4*)xb + (size_t)t * 256;
  float a[E_NUM];
#pragma unroll
  for (int e = 0; e < E_NUM; ++e) a[e] = 0.f;
#pragma unroll
  for (int j = 0; j < 4; ++j) {
    float4 v = xr4[lane + 64 * j];
    ushort4 o;
    o.x = f2b(v.x); o.y = f2b(v.y); o.z = f2b(v.z); o.w = f2b(v.w);
    xb4[lane + 64 * j] = o;
#pragma unroll
    for (int e = 0; e < E_NUM; ++e) {
      float4 wv4 = ((const float4*)(wt + (size_t)e * H_DIM))[lane + 64 * j];
      a[e] += v.x * wv4.x + v.y * wv4.y + v.z * wv4.z + v.w * wv4.w;
    }
  }
#pragma unroll
  for (int e = 0; e < E_NUM; ++e)
    for (int off = 32; off; off >>= 1) a[e] += __shfl_xor(a[e], off, 64);
  float lge = 0.f;
  int b = t / S_SEQ;
  if (lane < E_NUM) {
    const float* gv = g + b * G_DIM;
    const float* wv2 = wgm + lane * G_DIM;
    for (int i = 0; i < G_DIM; ++i) lge += gv[i] * wv2[i];
  }
  float l[E_NUM];
#pragma unroll
  for (int e = 0; e < E_NUM; ++e) l[e] = 0.5f * (a[e] + __shfl(lge, e, 64));
  if (lane == 0) {
    int i1 = 0; float b1 = l[0];
#pragma unroll
    for (int e = 1; e < E_NUM; ++e) if (l[e] > b1) { b1 = l[e]; i1 = e; }
    int i2 = -1; float b2 = -1e30f;
#pragma unroll
    for (int e = 0; e < E_NUM; ++e) if (e != i1 && l[e] > b2) { b2 = l[e]; i2 = e; }
    float e2 = expf(b2 - b1);            // e1 = 1
    float inv = 1.f / (1.f + e2);
    tidx[t * 2] = i1; tidx[t * 2 + 1] = i2;
    tw[t * 2] = inv;  tw[t * 2 + 1] = e2 * inv;
    int chunk = t >> 7;  // 128 tokens (= 256 assignments) per place-block
    atomicAdd(&bcount[chunk * E_NUM + i1], 1);
    atomicAdd(&bcount[chunk * E_NUM + i2], 1);
  }
}

// stable parallel compaction + inline scan: each block redundantly scans bcount;
// block 0 additionally emits tile descriptors.
__global__ __launch_bounds__(256) void place2_kernel(
    const int* __restrict__ tidx, const int* __restrict__ bcount,
    int* __restrict__ perm, int* __restrict__ slot_of,
    TileDesc* __restrict__ desc, int* __restrict__ ndesc) {
  __shared__ int cnt[E_NUM];
  __shared__ int myoff[E_NUM];
  __shared__ int wcnt[4][E_NUM];
  int tid = threadIdx.x, wv = tid >> 6, lane = tid & 63, blk = blockIdx.x;
  if (tid < E_NUM) {
    int run = 0, mine = 0;
    for (int b = 0; b < NBLK_PLACE; ++b) {
      if (b == blk) mine = run;
      run += bcount[b * E_NUM + tid];
    }
    cnt[tid] = run;
    myoff[tid] = mine;
  }
  __syncthreads();
  if (tid < E_NUM) {
    int o = 0;
    for (int e = 0; e < tid; ++e) o += cnt[e];
    myoff[tid] += o;
  }
  if (blk == 0 && tid == 32) {
    int o = 0, nd = 0;
    for (int e = 0; e < E_NUM; ++e) {
      int n = cnt[e];
      for (int tb = 0; tb < n; tb += 256) {
        desc[nd].base = o + tb; desc[nd].expert = e;
        desc[nd].nrows = imin(n - tb, 256);
        ++nd;
      }
      o += n;
    }
    *ndesc = nd;
  }
  int i = blk * 256 + tid;
  int e = tidx[i];
  unsigned long long lower = (lane == 63) ? 0x7fffffffffffffffull : ((1ull << lane) - 1ull);
  int rank = 0;
#pragma unroll
  for (int ee = 0; ee < E_NUM; ++ee) {
    unsigned long long m = __ballot(e == ee);
    if (e == ee) rank = __popcll(m & lower);
    if (lane == 0) wcnt[wv][ee] = __popcll(m);
  }
  __syncthreads();
  int off = myoff[e];
  for (int w = 0; w < wv; ++w) off += wcnt[w][e];
  int pos = off + rank;
  perm[pos] = i >> 1;
  slot_of[i] = pos;
}

// ======== GEMM core: BM=256, BN=256(virt), BK=64, 8 waves ========
// Relaxed sync: ONE barrier + ONE vmcnt per K-tile. All reads hit buf[cur];
// staging targets buf[nxt] (no conflict). Barrier at tile end orders reads of
// buf[cur] before it becomes the staging target next tile; reads complete
// before each wave's last MFMA issues, so no lgkm drain is needed.
template <int DUAL>
static __device__ __forceinline__ void gemm_core8(
    const ushort* __restrict__ A, const ushort* __restrict__ B0,
    const ushort* __restrict__ B1, void* __restrict__ Out, int outf32,
    int Kd, int NdOut, int rowbase, int nrows, int n0,
    const int* __restrict__ perm, ushort* __restrict__ LDS) {
  int tid = threadIdx.x, wv = tid >> 6, lane = tid & 63;
  int wr = wv >> 2, wc = wv & 3;
  int lr = lane & 15, cg = lane >> 4;
  int sid = lane >> 3, dch = lane & 7;

  // staging source pointers [piece][round]
  const ushort* apA[2][2];
  const ushort* apB[2][2];
#pragma unroll
  for (int qm = 0; qm < 2; ++qm)
#pragma unroll
    for (int k = 0; k < 2; ++k) {
      int idx = k * 64 + wv * 8 + sid;
      int gch = dch ^ (idx & 7);
      int grow = (idx >> 6) * 128 + qm * 64 + (idx & 63);
      grow = imin(grow, nrows - 1);
      int arow = perm ? perm[rowbase + grow] : rowbase + grow;
      apA[qm][k] = A + (size_t)arow * Kd + gch * 8;
    }
#pragma unroll
  for (int qn = 0; qn < 2; ++qn)
#pragma unroll
    for (int k = 0; k < 2; ++k) {
      int idx = k * 64 + wv * 8 + sid;
      int gch = dch ^ (idx & 7);
      int vrow = n0 + (idx >> 5) * 64 + qn * 32 + (idx & 31);
      const ushort* src; int brow;
      if (DUAL) {
        src = ((vrow >> 4) & 1) ? B1 : B0;
        brow = (vrow >> 5) * 16 + (vrow & 15);
      } else {
        src = B0; brow = vrow;
      }
      apB[qn][k] = src + (size_t)brow * Kd + gch * 8;
    }

  auto stgA = [&](int qm, int k, int nd) {
    gll16(apA[qm][k], LDS + nd * 16384 + qm * 8192 + (k * 512 + wv * 64) * 8);
    apA[qm][k] += 64;
  };
  auto stgB = [&](int qn, int k, int nd) {
    gll16(apB[qn][k], LDS + 32768 + nd * 16384 + qn * 8192 + (k * 512 + wv * 64) * 8);
    apB[qn][k] += 64;
  };
  auto rdA = [&](int d, int qm, int m, int kk) -> bf16x8 {
    int idx = wr * 64 + m * 16 + lr;
    int ch = (kk * 4 + cg) ^ (idx & 7);
    return *(const bf16x8*)(LDS + d * 16384 + qm * 8192 + idx * 64 + ch * 8);
  };
  auto rdB = [&](int d, int qn, int n, int kk) -> bf16x8 {
    int idx = wc * 32 + n * 16 + lr;
    int ch = (kk * 4 + cg) ^ (idx & 7);
    return *(const bf16x8*)(LDS + 32768 + d * 16384 + qn * 8192 + idx * 64 + ch * 8);
  };

  f32x4 acc[2][2][4][2];
#pragma unroll
  for (int qm = 0; qm < 2; ++qm)
#pragma unroll
    for (int qn = 0; qn < 2; ++qn)
#pragma unroll
      for (int m = 0; m < 4; ++m)
#pragma unroll
        for (int n = 0; n < 2; ++n) acc[qm][qn][m][n] = (f32x4){0.f, 0.f, 0.f, 0.f};

  int nk = Kd >> 6;
  // prologue: stage tile 0 into buf 0
  stgA(0, 0, 0); stgA(0, 1, 0);
  stgB(0, 0, 0); stgB(0, 1, 0);
  stgB(1, 0, 0); stgB(1, 1, 0);
  stgA(1, 0, 0); stgA(1, 1, 0);
  WAITCNT_VM0;
  __builtin_amdgcn_s_barrier();

  for (int t = 0; t < nk; ++t) {
    int cur = t & 1, nxt = cur ^ 1;
    bool hn = (t + 1 < nk);
    bf16x8 a0f[4][2], a1f[4][2], b0f[2][2], b1f[2][2];

    // issue next-tile staging first: loads fly under this tile's compute
    if (hn) {
      stgA(0, 0, nxt); stgA(0, 1, nxt);
      stgB(0, 0, nxt); stgB(0, 1, nxt);
      stgB(1, 0, nxt); stgB(1, 1, nxt);
      stgA(1, 0, nxt); stgA(1, 1, nxt);
    }

    // quadrant Q(0,0)
#pragma unroll
    for (int n = 0; n < 2; ++n) { b0f[n][0] = rdB(cur, 0, n, 0); b0f[n][1] = rdB(cur, 0, n, 1); }
#pragma unroll
    for (int m = 0; m < 4; ++m) { a0f[m][0] = rdA(cur, 0, m, 0); a0f[m][1] = rdA(cur, 0, m, 1); }
    __builtin_amdgcn_s_setprio(1);
#pragma unroll
    for (int m = 0; m < 4; ++m)
#pragma unroll
      for (int n = 0; n < 2; ++n) {
        acc[0][0][m][n] = __builtin_amdgcn_mfma_f32_16x16x32_bf16(a0f[m][0], b0f[n][0], acc[0][0][m][n], 0, 0, 0);
        acc[0][0][m][n] = __builtin_amdgcn_mfma_f32_16x16x32_bf16(a0f[m][1], b0f[n][1], acc[0][0][m][n], 0, 0, 0);
      }
    __builtin_amdgcn_s_setprio(0);

    // quadrant Q(0,1)
#pragma unroll
    for (int n = 0; n < 2; ++n) { b1f[n][0] = rdB(cur, 1, n, 0); b1f[n][1] = rdB(cur, 1, n, 1); }
    __builtin_amdgcn_s_setprio(1);
#pragma unroll
    for (int m = 0; m < 4; ++m)
#pragma unroll
      for (int n = 0; n < 2; ++n) {
        acc[0][1][m][n] = __builtin_amdgcn_mfma_f32_16x16x32_bf16(a0f[m][0], b1f[n][0], acc[0][1][m][n], 0, 0, 0);
        acc[0][1][m][n] = __builtin_amdgcn_mfma_f32_16x16x32_bf16(a0f[m][1], b1f[n][1], acc[0][1][m][n], 0, 0, 0);
      }
    __builtin_amdgcn_s_setprio(0);

    // quadrant Q(1,0)
#pragma unroll
    for (int m = 0; m < 4; ++m) { a1f[m][0] = rdA(cur, 1, m, 0); a1f[m][1] = rdA(cur, 1, m, 1); }
    __builtin_amdgcn_s_setprio(1);
#pragma unroll
    for (int m = 0; m < 4; ++m)
#pragma unroll
      for (int n = 0; n < 2; ++n) {
        acc[1][0][m][n] = __builtin_amdgcn_mfma_f32_16x16x32_bf16(a1f[m][0], b0f[n][0], acc[1][0][m][n], 0, 0, 0);
        acc[1][0][m][n] = __builtin_amdgcn_mfma_f32_16x16x32_bf16(a1f[m][1], b0f[n][1], acc[1][0][m][n], 0, 0, 0);
      }
    __builtin_amdgcn_s_setprio(0);

    // quadrant Q(1,1)
    __builtin_amdgcn_s_setprio(1);
#pragma unroll
    for (int m = 0; m < 4; ++m)
#pragma unroll
      for (int n = 0; n < 2; ++n) {
        acc[1][1][m][n] = __builtin_amdgcn_mfma_f32_16x16x32_bf16(a1f[m][0], b1f[n][0], acc[1][1][m][n], 0, 0, 0);
        acc[1][1][m][n] = __builtin_amdgcn_mfma_f32_16x16x32_bf16(a1f[m][1], b1f[n][1], acc[1][1][m][n], 0, 0, 0);
      }
    __builtin_amdgcn_s_setprio(0);

    if (hn) WAITCNT_VM0;           // tile t+1 landed (covered by this tile's MFMAs)
    __builtin_amdgcn_s_barrier();  // all reads of buf[cur] done before t+1 stages it
  }

  // epilogue (C/D layout: col=lane&15, row=(lane>>4)*4+reg)
#pragma unroll
  for (int qm = 0; qm < 2; ++qm)
#pragma unroll
    for (int qn = 0; qn < 2; ++qn)
#pragma unroll
      for (int m = 0; m < 4; ++m)
#pragma unroll
        for (int r = 0; r < 4; ++r) {
          int row = wr * 128 + qm * 64 + m * 16 + cg * 4 + r;
          if (row < nrows) {
            if (DUAL) {
              float gv = acc[qm][qn][m][0][r], uv = acc[qm][qn][m][1][r];
              float hv = (gv >= 0.f ? gv : 0.01f * gv) * uv;
              int col = ((n0 >> 5) + wc * 2 + qn) * 16 + lr;
              ((ushort*)Out)[(size_t)(rowbase + row) * NdOut + col] = f2b(hv);
            } else {
#pragma unroll
              for (int n = 0; n < 2; ++n) {
                int col = n0 + wc * 64 + qn * 32 + n * 16 + lr;
                size_t o = (size_t)(rowbase + row) * NdOut + col;
                if (outf32) ((float*)Out)[o] = acc[qm][qn][m][n][r];
                else ((ushort*)Out)[o] = f2b(acc[qm][qn][m][n][r]);
              }
            }
          }
        }
}

// merged dual: blocks [0,256) shared-expert, [256,544) routed experts
__global__ __launch_bounds__(512) void gemm_dual_all(
    const ushort* __restrict__ xb, const ushort* __restrict__ swg,
    const ushort* __restrict__ swu, ushort* __restrict__ hsh,
    const ushort* __restrict__ wg, const ushort* __restrict__ wu,
    ushort* __restrict__ h_e, const int* __restrict__ perm,
    const TileDesc* __restrict__ desc, const int* __restrict__ ndesc) {
  __shared__ ushort LDS[65536];  // 128 KB
  int id = xcd_remap(blockIdx.x, gridDim.x);
  if (id < 256) {
    int mt = id >> 3, n0 = (id & 7) * 256;
    gemm_core8<1>(xb, swg, swu, hsh, 0, H_DIM, SM_DIM, mt * 256, 256, n0, nullptr, LDS);
  } else {
    int rid = id - 256;
    int mt = rid >> 2, n0 = (rid & 3) * 256;
    if (mt >= *ndesc) return;
    TileDesc d = desc[mt];
    size_t wo = (size_t)d.expert * M_DIM * H_DIM;
    gemm_core8<1>(xb, wg + wo, wu + wo, h_e, 0, H_DIM, M_DIM, d.base, d.nrows, n0, perm, LDS);
  }
}

// merged down: blocks [0,128) shared (bf16 -> ysh), [128,416) routed (bf16 -> ye)
__global__ __launch_bounds__(512) void gemm_down_all(
    const ushort* __restrict__ hsh, const ushort* __restrict__ swd, ushort* __restrict__ ysh,
    const ushort* __restrict__ h_e, const ushort* __restrict__ wd, ushort* __restrict__ ye,
    const TileDesc* __restrict__ desc, const int* __restrict__ ndesc) {
  __shared__ ushort LDS[65536];  // 128 KB
  int id = xcd_remap(blockIdx.x, gridDim.x);
  if (id < 128) {
    int mt = id >> 2, n0 = (id & 3) * 256;
    gemm_core8<0>(hsh, swd, nullptr, (void*)ysh, 0, SM_DIM, H_DIM, mt * 256, 256, n0, nullptr, LDS);
  } else {
    int rid = id - 128;
    int mt = rid >> 2, n0 = (rid & 3) * 256;
    if (mt >= *ndesc) return;
    TileDesc d = desc[mt];
    gemm_core8<0>(h_e, wd + (size_t)d.expert * H_DIM * M_DIM, nullptr, (void*)ye, 0,
                  M_DIM, H_DIM, d.base, d.nrows, n0, nullptr, LDS);
  }
}

// y[t] = ysh[t] + w0*ye[s0] + w1*ye[s1]  (grid-stride, 2048 blocks)
__global__ __launch_bounds__(256) void final_kernel(
    float* __restrict__ y, const ushort* __restrict__ ysh, const ushort* __restrict__ ye,
    const int* __restrict__ slot_of, const float* __restrict__ tw) {
  for (int i = blockIdx.x * 256 + threadIdx.x; i < T_TOK * H_DIM / 4; i += 2048 * 256) {
    int t = i >> 8;
    int c4 = (i & 255) * 4;
    int s0 = slot_of[t * 2], s1 = slot_of[t * 2 + 1];
    float w0 = tw[t * 2], w1 = tw[t * 2 + 1];
    ushort4 pp = *(const ushort4*)(ysh + (size_t)t * H_DIM + c4);
    ushort4 a = *(const ushort4*)(ye + (size_t)s0 * H_DIM + c4);
    ushort4 b = *(const ushort4*)(ye + (size_t)s1 * H_DIM + c4);
    float4 v;
    v.x = b2f(pp.x) + w0 * b2f(a.x) + w1 * b2f(b.x);
    v.y = b2f(pp.y) + w0 * b2f(a.y) + w1 * b2f(b.y);
    v.z = b2f(pp.z) + w0 * b2f(a.z) + w1 * b2f(b.z);
    v.w = b2f(pp.w) + w0 * b2f(a.w) + w1 * b2f(b.w);
    ((float4*)y)[i] = v;
  }
}

// ---------------- host ----------------
extern "C" void kernel_launch(void* const* d_in, const int* in_sizes, int n_in,
                              void* d_out, int out_size, void* d_ws, size_t ws_size,
                              hipStream_t stream) {
  const float* x       = (const float*)d_in[0];
  const float* g       = (const float*)d_in[1];
  const float* wt      = (const float*)d_in[2];
  const float* wg      = (const float*)d_in[3];
  const float* w_gate  = (const float*)d_in[4];
  const float* w_up    = (const float*)d_in[5];
  const float* w_down  = (const float*)d_in[6];
  const float* sw_gate = (const float*)d_in[7];
  const float* sw_up   = (const float*)d_in[8];
  const float* sw_down = (const float*)d_in[9];
  float* y = (float*)d_out;

  char* p = (char*)d_ws;
  auto alloc = [&](size_t bytes) -> char* {
    char* r = p;
    p += (bytes + 255) & ~(size_t)255;
    return r;
  };
  ushort* xb    = (ushort*)alloc((size_t)T_TOK * H_DIM * 2);
  ushort* wg_t  = (ushort*)alloc((size_t)E_NUM * M_DIM * H_DIM * 2);  // (E, M, H)
  ushort* wu_t  = (ushort*)alloc((size_t)E_NUM * M_DIM * H_DIM * 2);
  ushort* wd_t  = (ushort*)alloc((size_t)E_NUM * H_DIM * M_DIM * 2);  // (E, H, M)
  ushort* swg_t = (ushort*)alloc((size_t)SM_DIM * H_DIM * 2);         // (SM, H)
  ushort* swu_t = (ushort*)alloc((size_t)SM_DIM * H_DIM * 2);
  ushort* swd_t = (ushort*)alloc((size_t)H_DIM * SM_DIM * 2);         // (H, SM)
  int* tidx     = (int*)alloc(NASSIGN * 4);
  float* tw     = (float*)alloc(NASSIGN * 4);
  int* bcount   = (int*)alloc(NBLK_PLACE * E_NUM * 4);
  int* ndesc    = (int*)alloc(4);
  int* perm     = (int*)alloc(NASSIGN * 4);
  int* slot_of  = (int*)alloc(NASSIGN * 4);
  TileDesc* desc = (TileDesc*)alloc(MAX_TILES * sizeof(TileDesc));
  ushort* h_e   = (ushort*)alloc((size_t)NSLOT * M_DIM * 2);
  ushort* hsh   = (ushort*)alloc((size_t)T_TOK * SM_DIM * 2);
  ushort* ye    = (ushort*)alloc((size_t)NSLOT * H_DIM * 2);
  ushort* ysh   = (ushort*)alloc((size_t)T_TOK * H_DIM * 2);
  (void)ws_size; (void)in_sizes; (void)n_in; (void)out_size;

  // zero expert histogram, then prep (weight transposes + router + hist)
  hipMemsetAsync(bcount, 0, NBLK_PLACE * E_NUM * 4, stream);
  prep_kernel<<<NT_W + 2048, 256, 0, stream>>>(
      x, wt, g, wg, w_gate, w_up, w_down, sw_gate, sw_up, sw_down,
      wg_t, wu_t, wd_t, swg_t, swu_t, swd_t, xb, tidx, tw, bcount);
  place2_kernel<<<NBLK_PLACE, 256, 0, stream>>>(tidx, bcount, perm, slot_of, desc, ndesc);

  // fused gate/up duals (shared + routed in one launch)
  gemm_dual_all<<<256 + MAX_TILES * 4, 512, 0, stream>>>(
      xb, swg_t, swu_t, hsh, wg_t, wu_t, h_e, perm, desc, ndesc);
  // down projections (shared -> ysh bf16, routed -> ye bf16, one launch)
  gemm_down_all<<<128 + MAX_TILES * 4, 512, 0, stream>>>(
      hsh, swd_t, ysh, h_e, wd_t, ye, desc, ndesc);

  // combine
  final_kernel<<<2048, 256, 0, stream>>>(y, ysh, ye, slot_of, tw);
}

// Round 11
// 208.931 us; speedup vs baseline: 1.0455x; 1.0455x over previous
//
#include <hip/hip_runtime.h>
#include <stdint.h>

// Problem constants (B=4, S=2048, H=1024, E=8, M=512, K=2, SM=1024, G=64)
#define T_TOK 8192
#define H_DIM 1024
#define M_DIM 512
#define SM_DIM 1024
#define E_NUM 8
#define S_SEQ 2048
#define G_DIM 64
#define NASSIGN 16384                      // T_TOK * 2
#define NSLOT (NASSIGN + E_NUM * 256)      // compact slots + per-expert 256-tile padding
#define MAX_TILES (NASSIGN / 256 + E_NUM)  // 72
#define NBLK_PLACE (NASSIGN / 256)         // 64
#define NT_W 3840                          // 64x64 weight transpose tiles

typedef float f32x4 __attribute__((ext_vector_type(4)));
typedef short bf16x8 __attribute__((ext_vector_type(8)));

struct TileDesc { int base; int expert; int nrows; };

#define WAITCNT_VM6 asm volatile("s_waitcnt vmcnt(6)" ::: "memory")
#define WAITCNT_VM4 asm volatile("s_waitcnt vmcnt(4)" ::: "memory")
#define WAITCNT_VM2 asm volatile("s_waitcnt vmcnt(2)" ::: "memory")
#define WAITCNT_VM0 asm volatile("s_waitcnt vmcnt(0)" ::: "memory")

static __device__ __forceinline__ ushort f2b(float f) {
  union { float f; uint32_t u; } a; a.f = f;
  uint32_t r = a.u + 0x7fffu + ((a.u >> 16) & 1u);  // RNE
  return (ushort)(r >> 16);
}
static __device__ __forceinline__ float b2f(ushort u) {
  union { uint32_t u; float f; } a; a.u = ((uint32_t)u) << 16;
  return a.f;
}
static __device__ __forceinline__ int imin(int a, int b) { return a < b ? a : b; }

// async global->LDS, 16B per lane; LDS dest = wave-uniform base + lane*16
static __device__ __forceinline__ void gll16(const void* g, void* l) {
  __builtin_amdgcn_global_load_lds(
      (const __attribute__((address_space(1))) void*)g,
      (__attribute__((address_space(3))) void*)l, 16, 0, 0);
}
// XCD-chunked bijective remap (nwg divisible by 8)
static __device__ __forceinline__ int xcd_remap(int wg, int nwg) {
  return (wg & 7) * (nwg >> 3) + (wg >> 3);
}

// ---------------- prep: 64x64 weight transpose tiles + fused router + hist ----------
__global__ __launch_bounds__(256) void prep_kernel(
    const float* __restrict__ x, const float* __restrict__ wt, const float* __restrict__ g,
    const float* __restrict__ wgm,
    const float* __restrict__ w_gate, const float* __restrict__ w_up,
    const float* __restrict__ w_down, const float* __restrict__ sw_gate,
    const float* __restrict__ sw_up, const float* __restrict__ sw_down,
    ushort* __restrict__ wg_t, ushort* __restrict__ wu_t,
    ushort* __restrict__ wd_t, ushort* __restrict__ swg_t,
    ushort* __restrict__ swu_t, ushort* __restrict__ swd_t,
    ushort* __restrict__ xb, int* __restrict__ tidx, float* __restrict__ tw,
    int* __restrict__ bcount) {
  __shared__ float tile[64][65];
  int id = blockIdx.x;
  int tid = threadIdx.x;
  if (id < NT_W) {
    int tx = tid & 15, ty = tid >> 4;
    const float* src; ushort* dst; int R, C, t;
    if (id < 1024)        { src = w_gate;  dst = wg_t;  R = 1024; C = 512;  t = id; }
    else if (id < 2048)   { src = w_up;    dst = wu_t;  R = 1024; C = 512;  t = id - 1024; }
    else if (id < 3072)   { src = w_down;  dst = wd_t;  R = 512;  C = 1024; t = id - 2048; }
    else if (id < 3328)   { src = sw_gate; dst = swg_t; R = 1024; C = 1024; t = id - 3072; }
    else if (id < 3584)   { src = sw_up;   dst = swu_t; R = 1024; C = 1024; t = id - 3328; }
    else                  { src = sw_down; dst = swd_t; R = 1024; C = 1024; t = id - 3584; }
    int tc = C >> 6;
    int tpm = (R >> 6) * tc;
    int e = t / tpm, tt = t % tpm;
    int c0 = (tt % tc) * 64, r0 = (tt / tc) * 64;
    size_t bo = (size_t)e * R * C;
    src += bo; dst += bo;
#pragma unroll
    for (int p = 0; p < 4; ++p) {
      int row = ty + p * 16;
      float4 v = *(const float4*)&src[(size_t)(r0 + row) * C + c0 + tx * 4];
      tile[row][tx * 4 + 0] = v.x; tile[row][tx * 4 + 1] = v.y;
      tile[row][tx * 4 + 2] = v.z; tile[row][tx * 4 + 3] = v.w;
    }
    __syncthreads();
#pragma unroll
    for (int p = 0; p < 4; ++p) {
      int cc = ty + p * 16;
      ushort4 o;
      o.x = f2b(tile[tx * 4 + 0][cc]); o.y = f2b(tile[tx * 4 + 1][cc]);
      o.z = f2b(tile[tx * 4 + 2][cc]); o.w = f2b(tile[tx * 4 + 3][cc]);
      *(ushort4*)&dst[(size_t)(c0 + cc) * R + r0 + tx * 4] = o;
    }
    return;
  }
  // ---- router (4 tokens per block, 1 wave each) ----
  int id2 = id - NT_W;
  int wv = tid >> 6, lane = tid & 63;
  int t = id2 * 4 + wv;
  const float4* xr4 = (const float4*)x + (size_t)t * 256;
  ushort4* xb4 = (ushort4*)xb + (size_t)t * 256;
  float a[E_NUM];
#pragma unroll
  for (int e = 0; e < E_NUM; ++e) a[e] = 0.f;
#pragma unroll
  for (int j = 0; j < 4; ++j) {
    float4 v = xr4[lane + 64 * j];
    ushort4 o;
    o.x = f2b(v.x); o.y = f2b(v.y); o.z = f2b(v.z); o.w = f2b(v.w);
    xb4[lane + 64 * j] = o;
#pragma unroll
    for (int e = 0; e < E_NUM; ++e) {
      float4 wv4 = ((const float4*)(wt + (size_t)e * H_DIM))[lane + 64 * j];
      a[e] += v.x * wv4.x + v.y * wv4.y + v.z * wv4.z + v.w * wv4.w;
    }
  }
#pragma unroll
  for (int e = 0; e < E_NUM; ++e)
    for (int off = 32; off; off >>= 1) a[e] += __shfl_xor(a[e], off, 64);
  float lge = 0.f;
  int b = t / S_SEQ;
  if (lane < E_NUM) {
    const float* gv = g + b * G_DIM;
    const float* wv2 = wgm + lane * G_DIM;
    for (int i = 0; i < G_DIM; ++i) lge += gv[i] * wv2[i];
  }
  float l[E_NUM];
#pragma unroll
  for (int e = 0; e < E_NUM; ++e) l[e] = 0.5f * (a[e] + __shfl(lge, e, 64));
  if (lane == 0) {
    int i1 = 0; float b1 = l[0];
#pragma unroll
    for (int e = 1; e < E_NUM; ++e) if (l[e] > b1) { b1 = l[e]; i1 = e; }
    int i2 = -1; float b2 = -1e30f;
#pragma unroll
    for (int e = 0; e < E_NUM; ++e) if (e != i1 && l[e] > b2) { b2 = l[e]; i2 = e; }
    float e2 = expf(b2 - b1);            // e1 = 1
    float inv = 1.f / (1.f + e2);
    tidx[t * 2] = i1; tidx[t * 2 + 1] = i2;
    tw[t * 2] = inv;  tw[t * 2 + 1] = e2 * inv;
    int chunk = t >> 7;  // 128 tokens (= 256 assignments) per place-block
    atomicAdd(&bcount[chunk * E_NUM + i1], 1);
    atomicAdd(&bcount[chunk * E_NUM + i2], 1);
  }
}

// stable parallel compaction + inline scan (bcount staged in LDS cooperatively;
// block 0 additionally emits tile descriptors).
__global__ __launch_bounds__(256) void place2_kernel(
    const int* __restrict__ tidx, const int* __restrict__ bcount,
    int* __restrict__ perm, int* __restrict__ slot_of,
    TileDesc* __restrict__ desc, int* __restrict__ ndesc) {
  __shared__ int bc[NBLK_PLACE * E_NUM];  // 512 ints
  __shared__ int cnt[E_NUM];
  __shared__ int myoff[E_NUM];
  __shared__ int wcnt[4][E_NUM];
  int tid = threadIdx.x, wv = tid >> 6, lane = tid & 63, blk = blockIdx.x;
#pragma unroll
  for (int j = 0; j < NBLK_PLACE * E_NUM / 256; ++j)
    bc[tid + j * 256] = bcount[tid + j * 256];
  __syncthreads();
  if (tid < E_NUM) {
    int run = 0, mine = 0;
    for (int b = 0; b < NBLK_PLACE; ++b) {
      if (b == blk) mine = run;
      run += bc[b * E_NUM + tid];
    }
    cnt[tid] = run;
    myoff[tid] = mine;
  }
  __syncthreads();
  if (tid < E_NUM) {
    int o = 0;
    for (int e = 0; e < tid; ++e) o += cnt[e];
    myoff[tid] += o;
  }
  if (blk == 0 && tid == 32) {
    int o = 0, nd = 0;
    for (int e = 0; e < E_NUM; ++e) {
      int n = cnt[e];
      for (int tb = 0; tb < n; tb += 256) {
        desc[nd].base = o + tb; desc[nd].expert = e;
        desc[nd].nrows = imin(n - tb, 256);
        ++nd;
      }
      o += n;
    }
    *ndesc = nd;
  }
  int i = blk * 256 + tid;
  int e = tidx[i];
  unsigned long long lower = (lane == 63) ? 0x7fffffffffffffffull : ((1ull << lane) - 1ull);
  int rank = 0;
#pragma unroll
  for (int ee = 0; ee < E_NUM; ++ee) {
    unsigned long long m = __ballot(e == ee);
    if (e == ee) rank = __popcll(m & lower);
    if (lane == 0) wcnt[wv][ee] = __popcll(m);
  }
  __syncthreads();
  int off = myoff[e];
  for (int w = 0; w < wv; ++w) off += wcnt[w][e];
  int pos = off + rank;
  perm[pos] = i >> 1;
  slot_of[i] = pos;
}

// ======== GEMM core: BM=256, BN=256(virt), BK=64, 8 waves, 4-phase K-tile ========
// (round-8 measured-best core: counted vmcnt, no lgkm drains)
template <int DUAL>
static __device__ __forceinline__ void gemm_core8(
    const ushort* __restrict__ A, const ushort* __restrict__ B0,
    const ushort* __restrict__ B1, void* __restrict__ Out, int outf32,
    int Kd, int NdOut, int rowbase, int nrows, int n0,
    const int* __restrict__ perm, ushort* __restrict__ LDS) {
  int tid = threadIdx.x, wv = tid >> 6, lane = tid & 63;
  int wr = wv >> 2, wc = wv & 3;
  int lr = lane & 15, cg = lane >> 4;
  int sid = lane >> 3, dch = lane & 7;

  // staging source pointers [piece][round]
  const ushort* apA[2][2];
  const ushort* apB[2][2];
#pragma unroll
  for (int qm = 0; qm < 2; ++qm)
#pragma unroll
    for (int k = 0; k < 2; ++k) {
      int idx = k * 64 + wv * 8 + sid;
      int gch = dch ^ (idx & 7);
      int grow = (idx >> 6) * 128 + qm * 64 + (idx & 63);
      grow = imin(grow, nrows - 1);
      int arow = perm ? perm[rowbase + grow] : rowbase + grow;
      apA[qm][k] = A + (size_t)arow * Kd + gch * 8;
    }
#pragma unroll
  for (int qn = 0; qn < 2; ++qn)
#pragma unroll
    for (int k = 0; k < 2; ++k) {
      int idx = k * 64 + wv * 8 + sid;
      int gch = dch ^ (idx & 7);
      int vrow = n0 + (idx >> 5) * 64 + qn * 32 + (idx & 31);
      const ushort* src; int brow;
      if (DUAL) {
        src = ((vrow >> 4) & 1) ? B1 : B0;
        brow = (vrow >> 5) * 16 + (vrow & 15);
      } else {
        src = B0; brow = vrow;
      }
      apB[qn][k] = src + (size_t)brow * Kd + gch * 8;
    }

  auto stgA = [&](int qm, int k, int nd) {
    gll16(apA[qm][k], LDS + nd * 16384 + qm * 8192 + (k * 512 + wv * 64) * 8);
    apA[qm][k] += 64;
  };
  auto stgB = [&](int qn, int k, int nd) {
    gll16(apB[qn][k], LDS + 32768 + nd * 16384 + qn * 8192 + (k * 512 + wv * 64) * 8);
    apB[qn][k] += 64;
  };
  auto rdA = [&](int d, int qm, int m, int kk) -> bf16x8 {
    int idx = wr * 64 + m * 16 + lr;
    int ch = (kk * 4 + cg) ^ (idx & 7);
    return *(const bf16x8*)(LDS + d * 16384 + qm * 8192 + idx * 64 + ch * 8);
  };
  auto rdB = [&](int d, int qn, int n, int kk) -> bf16x8 {
    int idx = wc * 32 + n * 16 + lr;
    int ch = (kk * 4 + cg) ^ (idx & 7);
    return *(const bf16x8*)(LDS + 32768 + d * 16384 + qn * 8192 + idx * 64 + ch * 8);
  };

  f32x4 acc[2][2][4][2];
#pragma unroll
  for (int qm = 0; qm < 2; ++qm)
#pragma unroll
    for (int qn = 0; qn < 2; ++qn)
#pragma unroll
      for (int m = 0; m < 4; ++m)
#pragma unroll
        for (int n = 0; n < 2; ++n) acc[qm][qn][m][n] = (f32x4){0.f, 0.f, 0.f, 0.f};

  int nk = Kd >> 6;
  // prologue: stage tile 0 into dbuf 0, piece order A0,B0,B1,A1
  stgA(0, 0, 0); stgA(0, 1, 0);
  stgB(0, 0, 0); stgB(0, 1, 0);
  stgB(1, 0, 0); stgB(1, 1, 0);
  stgA(1, 0, 0); stgA(1, 1, 0);
  WAITCNT_VM4;  // A0,B0 landed
  __builtin_amdgcn_s_barrier();

  for (int t = 0; t < nk; ++t) {
    int cur = t & 1, nxt = cur ^ 1;
    bool hn = (t + 1 < nk);
    bf16x8 a0f[4][2], a1f[4][2], b0f[2][2], b1f[2][2];

    // ---- phase 0: read B0,A0; stage A0'; MFMA Q(0,0)
#pragma unroll
    for (int n = 0; n < 2; ++n) { b0f[n][0] = rdB(cur, 0, n, 0); b0f[n][1] = rdB(cur, 0, n, 1); }
#pragma unroll
    for (int m = 0; m < 4; ++m) { a0f[m][0] = rdA(cur, 0, m, 0); a0f[m][1] = rdA(cur, 0, m, 1); }
    if (hn) { stgA(0, 0, nxt); stgA(0, 1, nxt); WAITCNT_VM4; } else { WAITCNT_VM2; }
    __builtin_amdgcn_s_barrier();
    __builtin_amdgcn_s_setprio(1);
#pragma unroll
    for (int m = 0; m < 4; ++m)
#pragma unroll
      for (int n = 0; n < 2; ++n) {
        acc[0][0][m][n] = __builtin_amdgcn_mfma_f32_16x16x32_bf16(a0f[m][0], b0f[n][0], acc[0][0][m][n], 0, 0, 0);
        acc[0][0][m][n] = __builtin_amdgcn_mfma_f32_16x16x32_bf16(a0f[m][1], b0f[n][1], acc[0][0][m][n], 0, 0, 0);
      }
    __builtin_amdgcn_s_setprio(0);

    // ---- phase 1: read B1; stage B0'; MFMA Q(0,1)
#pragma unroll
    for (int n = 0; n < 2; ++n) { b1f[n][0] = rdB(cur, 1, n, 0); b1f[n][1] = rdB(cur, 1, n, 1); }
    if (hn) { stgB(0, 0, nxt); stgB(0, 1, nxt); WAITCNT_VM4; } else { WAITCNT_VM0; }
    __builtin_amdgcn_s_barrier();
    __builtin_amdgcn_s_setprio(1);
#pragma unroll
    for (int m = 0; m < 4; ++m)
#pragma unroll
      for (int n = 0; n < 2; ++n) {
        acc[0][1][m][n] = __builtin_amdgcn_mfma_f32_16x16x32_bf16(a0f[m][0], b1f[n][0], acc[0][1][m][n], 0, 0, 0);
        acc[0][1][m][n] = __builtin_amdgcn_mfma_f32_16x16x32_bf16(a0f[m][1], b1f[n][1], acc[0][1][m][n], 0, 0, 0);
      }
    __builtin_amdgcn_s_setprio(0);

    // ---- phase 2: read A1; stage B1'; MFMA Q(1,0)
#pragma unroll
    for (int m = 0; m < 4; ++m) { a1f[m][0] = rdA(cur, 1, m, 0); a1f[m][1] = rdA(cur, 1, m, 1); }
    if (hn) { stgB(1, 0, nxt); stgB(1, 1, nxt); WAITCNT_VM6; }
    __builtin_amdgcn_s_barrier();
    __builtin_amdgcn_s_setprio(1);
#pragma unroll
    for (int m = 0; m < 4; ++m)
#pragma unroll
      for (int n = 0; n < 2; ++n) {
        acc[1][0][m][n] = __builtin_amdgcn_mfma_f32_16x16x32_bf16(a1f[m][0], b0f[n][0], acc[1][0][m][n], 0, 0, 0);
        acc[1][0][m][n] = __builtin_amdgcn_mfma_f32_16x16x32_bf16(a1f[m][1], b0f[n][1], acc[1][0][m][n], 0, 0, 0);
      }
    __builtin_amdgcn_s_setprio(0);

    // ---- phase 3: stage A1'; MFMA Q(1,1)
    if (hn) { stgA(1, 0, nxt); stgA(1, 1, nxt); WAITCNT_VM4; }
    __builtin_amdgcn_s_barrier();
    __builtin_amdgcn_s_setprio(1);
#pragma unroll
    for (int m = 0; m < 4; ++m)
#pragma unroll
      for (int n = 0; n < 2; ++n) {
        acc[1][1][m][n] = __builtin_amdgcn_mfma_f32_16x16x32_bf16(a1f[m][0], b1f[n][0], acc[1][1][m][n], 0, 0, 0);
        acc[1][1][m][n] = __builtin_amdgcn_mfma_f32_16x16x32_bf16(a1f[m][1], b1f[n][1], acc[1][1][m][n], 0, 0, 0);
      }
    __builtin_amdgcn_s_setprio(0);
  }

  // epilogue (C/D layout: col=lane&15, row=(lane>>4)*4+reg)
#pragma unroll
  for (int qm = 0; qm < 2; ++qm)
#pragma unroll
    for (int qn = 0; qn < 2; ++qn)
#pragma unroll
      for (int m = 0; m < 4; ++m)
#pragma unroll
        for (int r = 0; r < 4; ++r) {
          int row = wr * 128 + qm * 64 + m * 16 + cg * 4 + r;
          if (row < nrows) {
            if (DUAL) {
              float gv = acc[qm][qn][m][0][r], uv = acc[qm][qn][m][1][r];
              float hv = (gv >= 0.f ? gv : 0.01f * gv) * uv;
              int col = ((n0 >> 5) + wc * 2 + qn) * 16 + lr;
              ((ushort*)Out)[(size_t)(rowbase + row) * NdOut + col] = f2b(hv);
            } else {
#pragma unroll
              for (int n = 0; n < 2; ++n) {
                int col = n0 + wc * 64 + qn * 32 + n * 16 + lr;
                size_t o = (size_t)(rowbase + row) * NdOut + col;
                if (outf32) ((float*)Out)[o] = acc[qm][qn][m][n][r];
                else ((ushort*)Out)[o] = f2b(acc[qm][qn][m][n][r]);
              }
            }
          }
        }
}

// merged dual: blocks [0,256) shared-expert, [256,544) routed experts
__global__ __launch_bounds__(512) void gemm_dual_all(
    const ushort* __restrict__ xb, const ushort* __restrict__ swg,
    const ushort* __restrict__ swu, ushort* __restrict__ hsh,
    const ushort* __restrict__ wg, const ushort* __restrict__ wu,
    ushort* __restrict__ h_e, const int* __restrict__ perm,
    const TileDesc* __restrict__ desc, const int* __restrict__ ndesc) {
  __shared__ ushort LDS[65536];  // 128 KB
  int id = xcd_remap(blockIdx.x, gridDim.x);
  if (id < 256) {
    int mt = id >> 3, n0 = (id & 7) * 256;
    gemm_core8<1>(xb, swg, swu, hsh, 0, H_DIM, SM_DIM, mt * 256, 256, n0, nullptr, LDS);
  } else {
    int rid = id - 256;
    int mt = rid >> 2, n0 = (rid & 3) * 256;
    if (mt >= *ndesc) return;
    TileDesc d = desc[mt];
    size_t wo = (size_t)d.expert * M_DIM * H_DIM;
    gemm_core8<1>(xb, wg + wo, wu + wo, h_e, 0, H_DIM, M_DIM, d.base, d.nrows, n0, perm, LDS);
  }
}

// merged down: blocks [0,128) shared (bf16 -> ysh), [128,416) routed (bf16 -> ye)
__global__ __launch_bounds__(512) void gemm_down_all(
    const ushort* __restrict__ hsh, const ushort* __restrict__ swd, ushort* __restrict__ ysh,
    const ushort* __restrict__ h_e, const ushort* __restrict__ wd, ushort* __restrict__ ye,
    const TileDesc* __restrict__ desc, const int* __restrict__ ndesc) {
  __shared__ ushort LDS[65536];  // 128 KB
  int id = xcd_remap(blockIdx.x, gridDim.x);
  if (id < 128) {
    int mt = id >> 2, n0 = (id & 3) * 256;
    gemm_core8<0>(hsh, swd, nullptr, (void*)ysh, 0, SM_DIM, H_DIM, mt * 256, 256, n0, nullptr, LDS);
  } else {
    int rid = id - 128;
    int mt = rid >> 2, n0 = (rid & 3) * 256;
    if (mt >= *ndesc) return;
    TileDesc d = desc[mt];
    gemm_core8<0>(h_e, wd + (size_t)d.expert * H_DIM * M_DIM, nullptr, (void*)ye, 0,
                  M_DIM, H_DIM, d.base, d.nrows, n0, nullptr, LDS);
  }
}

// y[t] = ysh[t] + w0*ye[s0] + w1*ye[s1]  (grid-stride, 2048 blocks)
__global__ __launch_bounds__(256) void final_kernel(
    float* __restrict__ y, const ushort* __restrict__ ysh, const ushort* __restrict__ ye,
    const int* __restrict__ slot_of, const float* __restrict__ tw) {
  for (int i = blockIdx.x * 256 + threadIdx.x; i < T_TOK * H_DIM / 4; i += 2048 * 256) {
    int t = i >> 8;
    int c4 = (i & 255) * 4;
    int s0 = slot_of[t * 2], s1 = slot_of[t * 2 + 1];
    float w0 = tw[t * 2], w1 = tw[t * 2 + 1];
    ushort4 pp = *(const ushort4*)(ysh + (size_t)t * H_DIM + c4);
    ushort4 a = *(const ushort4*)(ye + (size_t)s0 * H_DIM + c4);
    ushort4 b = *(const ushort4*)(ye + (size_t)s1 * H_DIM + c4);
    float4 v;
    v.x = b2f(pp.x) + w0 * b2f(a.x) + w1 * b2f(b.x);
    v.y = b2f(pp.y) + w0 * b2f(a.y) + w1 * b2f(b.y);
    v.z = b2f(pp.z) + w0 * b2f(a.z) + w1 * b2f(b.z);
    v.w = b2f(pp.w) + w0 * b2f(a.w) + w1 * b2f(b.w);
    ((float4*)y)[i] = v;
  }
}

// ---------------- host ----------------
extern "C" void kernel_launch(void* const* d_in, const int* in_sizes, int n_in,
                              void* d_out, int out_size, void* d_ws, size_t ws_size,
                              hipStream_t stream) {
  const float* x       = (const float*)d_in[0];
  const float* g       = (const float*)d_in[1];
  const float* wt      = (const float*)d_in[2];
  const float* wg      = (const float*)d_in[3];
  const float* w_gate  = (const float*)d_in[4];
  const float* w_up    = (const float*)d_in[5];
  const float* w_down  = (const float*)d_in[6];
  const float* sw_gate = (const float*)d_in[7];
  const float* sw_up   = (const float*)d_in[8];
  const float* sw_down = (const float*)d_in[9];
  float* y = (float*)d_out;

  char* p = (char*)d_ws;
  auto alloc = [&](size_t bytes) -> char* {
    char* r = p;
    p += (bytes + 255) & ~(size_t)255;
    return r;
  };
  ushort* xb    = (ushort*)alloc((size_t)T_TOK * H_DIM * 2);
  ushort* wg_t  = (ushort*)alloc((size_t)E_NUM * M_DIM * H_DIM * 2);  // (E, M, H)
  ushort* wu_t  = (ushort*)alloc((size_t)E_NUM * M_DIM * H_DIM * 2);
  ushort* wd_t  = (ushort*)alloc((size_t)E_NUM * H_DIM * M_DIM * 2);  // (E, H, M)
  ushort* swg_t = (ushort*)alloc((size_t)SM_DIM * H_DIM * 2);         // (SM, H)
  ushort* swu_t = (ushort*)alloc((size_t)SM_DIM * H_DIM * 2);
  ushort* swd_t = (ushort*)alloc((size_t)H_DIM * SM_DIM * 2);         // (H, SM)
  int* tidx     = (int*)alloc(NASSIGN * 4);
  float* tw     = (float*)alloc(NASSIGN * 4);
  int* bcount   = (int*)alloc(NBLK_PLACE * E_NUM * 4);
  int* ndesc    = (int*)alloc(4);
  int* perm     = (int*)alloc(NASSIGN * 4);
  int* slot_of  = (int*)alloc(NASSIGN * 4);
  TileDesc* desc = (TileDesc*)alloc(MAX_TILES * sizeof(TileDesc));
  ushort* h_e   = (ushort*)alloc((size_t)NSLOT * M_DIM * 2);
  ushort* hsh   = (ushort*)alloc((size_t)T_TOK * SM_DIM * 2);
  ushort* ye    = (ushort*)alloc((size_t)NSLOT * H_DIM * 2);
  ushort* ysh   = (ushort*)alloc((size_t)T_TOK * H_DIM * 2);
  (void)ws_size; (void)in_sizes; (void)n_in; (void)out_size;

  // zero expert histogram, then prep (weight transposes + router + hist)
  hipMemsetAsync(bcount, 0, NBLK_PLACE * E_NUM * 4, stream);
  prep_kernel<<<NT_W + 2048, 256, 0, stream>>>(
      x, wt, g, wg, w_gate, w_up, w_down, sw_gate, sw_up, sw_down,
      wg_t, wu_t, wd_t, swg_t, swu_t, swd_t, xb, tidx, tw, bcount);
  place2_kernel<<<NBLK_PLACE, 256, 0, stream>>>(tidx, bcount, perm, slot_of, desc, ndesc);

  // fused gate/up duals (shared + routed in one launch)
  gemm_dual_all<<<256 + MAX_TILES * 4, 512, 0, stream>>>(
      xb, swg_t, swu_t, hsh, wg_t, wu_t, h_e, perm, desc, ndesc);
  // down projections (shared -> ysh bf16, routed -> ye bf16, one launch)
  gemm_down_all<<<128 + MAX_TILES * 4, 512, 0, stream>>>(
      hsh, swd_t, ysh, h_e, wd_t, ye, desc, ndesc);

  // combine
  final_kernel<<<2048, 256, 0, stream>>>(y, ysh, ye, slot_of, tw);
}